// Round 11
// baseline (2221.515 us; speedup 1.0000x reference)
//
#include <hip/hip_runtime.h>
#include <stdint.h>
#include <stddef.h>

#define HH 3840
#define AH 1920
#define NI 18
#define NT 256
#define NBATCH 64
#define KMAX 224      // ELL capacity per row, incl. 18 input entries
#define JSLOT 28      // KMAX/8 per-lane entry slots
#define NRW 120       // rows per block
#define NB 8          // batches per group
#define NGROUP 16     // 2 areas * 8 batch-tiles
#define NBLK_G 16     // blocks per group
#define NBLOCKS 256
#define NTHREADS 1024
#define COLS 1920
#define COLT 1938     // 1920 h cols + 18 x cols
#define HNEW_PAD 9

// ---- ws layout (bytes) ----
#define ENT_BYTES ((size_t)HH * KMAX * 4)            // 3,440,640
#define CNT_BYTES ((size_t)HH * 4)                   // 15,360
#define XT2_BYTES ((size_t)NT * NI * NBATCH * 2)     // 589,824 (f16)
#define HT_HALF   ((size_t)NGROUP * AH * NB)         // u16 elems per buffer = 245,760
#define HT_BYTES  (2 * HT_HALF * 2)                  // 983,040 (double buffered)
#define FLAG_ELEMS ((size_t)NGROUP * NBLK_G * 32)    // 8192 (16 words/block used)
#define PC_ELEMS  16

// ---- LDS (dynamic) ----
#define SLAB_B    (COLT * 16)                // 31,008 per buffer
#define OFF_HNEW  (2 * SLAB_B)               // 62,016
#define HNEW_B    (2 * NRW * HNEW_PAD * 4)   // 8,640 (double buffered)
#define SMEM_USED (OFF_HNEW + HNEW_B)        // 70,656
#define SMEM_ALLOC 83968                     // force 1 block/CU

#define AS1 __attribute__((address_space(1)))
#define AS3 __attribute__((address_space(3)))

typedef unsigned long long u64;

__device__ __forceinline__ float lo16(uint32_t u) {
    union { uint16_t q; _Float16 h; } c; c.q = (uint16_t)u; return (float)c.h;
}
__device__ __forceinline__ uint16_t f2h_bits(float f) {
    union { _Float16 h; uint16_t u; } c; c.h = (_Float16)f; return c.u;
}
__device__ __forceinline__ uint32_t pkrtz(float x, float y) {
    typedef __fp16 h2 __attribute__((ext_vector_type(2)));
    union { h2 h; uint32_t u; } c; c.h = __builtin_amdgcn_cvt_pkrtz(x, y); return c.u;
}
__device__ __forceinline__ void gll16(const void* g, void* l) {
    __builtin_amdgcn_global_load_lds((const AS1 uint32_t*)g, (AS3 uint32_t*)l, 16, 0, 0);
}
__device__ __forceinline__ void astore(u64* p, u64 v) {
    __hip_atomic_store(p, v, __ATOMIC_RELAXED, __HIP_MEMORY_SCOPE_AGENT);
}
#define SWZ(v, pat) __uint_as_float(__builtin_amdgcn_ds_swizzle(__float_as_uint(v), pat))
#define DPA(c, ctrl) c += __uint_as_float(__builtin_amdgcn_mov_dpp(__float_as_uint(c), ctrl, 0xF, 0xF, true))
// single-instruction f16(lo/hi of %1) * f32(%2) + f32 acc
#define FMIX_LO(acc, h2, w) asm("v_fma_mix_f32 %0, %1, %2, %0 op_sel:[0,0,0] op_sel_hi:[1,0,0]" : "+v"(acc) : "v"(h2), "v"(w))
#define FMIX_HI(acc, h2, w) asm("v_fma_mix_f32 %0, %1, %2, %0 op_sel:[1,0,0] op_sel_hi:[1,0,0]" : "+v"(acc) : "v"(h2), "v"(w))

__global__ void init_ws_kernel(uint32_t* __restrict__ flg, uint32_t* __restrict__ ht0) {
    size_t i = (size_t)blockIdx.x * blockDim.x + threadIdx.x;
    if (i < FLAG_ELEMS + PC_ELEMS) flg[i] = 0;
    if (i < HT_HALF / 2) ht0[i] = 0;   // zero h buffer 0 (h_{-1} = 0), u32 view
}

// one wave per destination row: ballot+popc packing of nonzero mask entries
__global__ void build_ell_kernel(const float* __restrict__ Whh, const float* __restrict__ mask,
                                 const float* __restrict__ Wih,
                                 uint32_t* __restrict__ ent, uint32_t* __restrict__ cnt) {
    int gw = (int)((blockIdx.x * blockDim.x + threadIdx.x) >> 6);
    int lane = threadIdx.x & 63;
    if (gw >= HH) return;
    const int d = gw;
    const int area = (d >= AH) ? 1 : 0;
    const float* mrow = mask + (size_t)d * HH + (size_t)area * AH;
    const float* wrow = Whh + (size_t)d * HH + (size_t)area * AH;
    uint32_t* erow = ent + (size_t)d * KMAX;
    uint32_t base = 0;
    for (int c0 = 0; c0 < AH; c0 += 64) {
        int c = c0 + lane;
        float m = mrow[c];
        bool pred = (m != 0.0f);
        uint64_t mk = __ballot(pred);
        if (pred) {
            uint32_t pos = base + (uint32_t)__popcll(mk & ((1ull << lane) - 1ull));
            if (pos < KMAX) erow[pos] = ((uint32_t)c << 16) | (uint32_t)f2h_bits(wrow[c] * m);
        }
        base += (uint32_t)__popcll(mk);
    }
    if (lane < NI) {   // fold input projection as extra "columns"
        uint32_t pos = base + (uint32_t)lane;
        if (pos < KMAX)
            erow[pos] = ((uint32_t)(COLS + lane) << 16) | (uint32_t)f2h_bits(Wih[(size_t)d * NI + lane]);
    }
    base += NI;
    if (lane == 0) cnt[d] = (base < KMAX) ? base : KMAX;
}

__global__ void xt_kernel(const float* __restrict__ x, uint16_t* __restrict__ xT2) {
    int i = blockIdx.x * blockDim.x + threadIdx.x;  // [t][i][b]
    if (i >= NT * NI * NBATCH) return;
    int b = i % NBATCH;
    int rest = i / NBATCH;
    int ii = rest % NI;
    int t = rest / NI;
    xT2[i] = f2h_bits(x[((size_t)b * NT + t) * NI + ii]);
}

__global__ __launch_bounds__(NTHREADS, 4) void rnn_kernel(
    const uint32_t* __restrict__ ent, const uint32_t* __restrict__ cnt,
    const uint16_t* __restrict__ xT2, uint16_t* __restrict__ hT,
    uint32_t* __restrict__ flg,
    const float* __restrict__ bih, const float* __restrict__ bhh,
    float* __restrict__ out)
{
    extern __shared__ char smem[];
    uint4* slab = (uint4*)smem;                  // [2][COLT] f16x8
    float* hnew = (float*)(smem + OFF_HNEW);     // [2][NRW][9]

    const int tid = threadIdx.x;
    const int G = blockIdx.x & 15, role = blockIdx.x >> 4;   // placement-independent
    const int a = G >> 3, g = G & 7;
    const int row0 = role * NRW;                 // area-local

    const int wv = tid >> 6, lane = tid & 63;
    const int ro = lane >> 3;          // 0..7 row within wave
    const int kq = lane & 7;           // 0..7 k-stripe
    const int r  = wv * 8 + ro;        // block-local row (valid for wv < 15)

    uint32_t* myflag = flg + ((size_t)G * NBLK_G + role) * 16 + wv;  // per-wave flag

    // ---- hoist step-invariant entries into VGPRs ----
    float wj[JSLOT];
    int   aj[JSLOT];
    float biasr = 0.f;
    int wm = 0;
    if (wv < 15) {
        const int gRow = a * AH + row0 + r;
        const int n = (int)cnt[gRow];
        biasr = bih[gRow] + bhh[gRow];
        int jmax = (n > kq) ? ((n - kq + 7) >> 3) : 0;
        const uint32_t* ep = ent + (size_t)gRow * KMAX;
        #pragma unroll
        for (int j = 0; j < JSLOT; ++j) {
            uint32_t e = (j < jmax) ? ep[kq + 8 * j] : 0u;
            aj[j] = (int)((e >> 16) * 16);           // byte offset within one slab buffer
            wj[j] = (j < jmax) ? lo16(e) : 0.0f;
        }
        wm = jmax;
        #pragma unroll
        for (int s = 1; s < 64; s <<= 1) {
            int ov = __shfl_xor(wm, s, 64);
            wm = (ov > wm) ? ov : wm;                // wave-uniform trip count
        }
    }

    for (int t = 0; t < NT; ++t) {
        const int cur = t & 1, nxt = cur ^ 1;
        // ---- x tail for this step (const data, DMA into current slab) ----
        if (wv == 0 && lane < NI)
            gll16(xT2 + ((size_t)t * NI + lane) * NBATCH + g * NB,
                  &slab[cur * COLT + COLS + lane]);
        // ---- per-wave poll (15 lanes x producer's 15 wave-flags) + stage ----
        if (wv >= 1 || t == 0) {
            const int p = (role + wv) & 15;
            if (t > 0) {
                const uint32_t* fb = flg + ((size_t)G * NBLK_G + p) * 16;
                bool ok = (lane >= 15);
                int guard = 0;
                while (!__all(ok) && guard < (1 << 20)) {
                    if (!ok)
                        ok = __hip_atomic_load(fb + lane, __ATOMIC_RELAXED,
                                               __HIP_MEMORY_SCOPE_AGENT) >= (uint32_t)t;
                    ++guard;
                }
            }
            const uint4* sp = (const uint4*)(hT + (size_t)cur * HT_HALF
                                             + ((size_t)G * AH + p * NRW) * NB);
            const int l2i = (lane < 56) ? (64 + lane) : lane;
            uint4 v0, v1;
            asm volatile("global_load_dwordx4 %0, %2, off sc0 sc1\n\t"
                         "global_load_dwordx4 %1, %3, off sc0 sc1\n\t"
                         "s_waitcnt vmcnt(0)"
                         : "=&v"(v0), "=&v"(v1)
                         : "v"(sp + lane), "v"(sp + l2i)
                         : "memory");
            uint4* dst = slab + cur * COLT + p * NRW;
            dst[lane] = v0;
            dst[l2i] = v1;
        }
        __syncthreads();   // slab[cur] complete (stage + self-copies + x-tail)

        if (wv < 15) {
            // ---- compute ----
            const char* sb = (const char*)(slab + cur * COLT);
            float c0 = 0.f, c1 = 0.f, c2 = 0.f, c3 = 0.f, c4 = 0.f, c5 = 0.f, c6 = 0.f, c7 = 0.f;
            #pragma unroll
            for (int j = 0; j < JSLOT; ++j) {
                if (j >= wm) break;
                const uint4 hv = *(const uint4*)(sb + aj[j]);
                const float wf = wj[j];
                FMIX_LO(c0, hv.x, wf); FMIX_HI(c1, hv.x, wf);
                FMIX_LO(c2, hv.y, wf); FMIX_HI(c3, hv.y, wf);
                FMIX_LO(c4, hv.z, wf); FMIX_HI(c5, hv.z, wf);
                FMIX_LO(c6, hv.w, wf); FMIX_HI(c7, hv.w, wf);
            }
            // reduce across kq: xor4 via ds_swizzle, xor2/xor1 via DPP quad_perm
            c0 += SWZ(c0, 0x101F); c1 += SWZ(c1, 0x101F); c2 += SWZ(c2, 0x101F); c3 += SWZ(c3, 0x101F);
            c4 += SWZ(c4, 0x101F); c5 += SWZ(c5, 0x101F); c6 += SWZ(c6, 0x101F); c7 += SWZ(c7, 0x101F);
            DPA(c0, 0x4E); DPA(c1, 0x4E); DPA(c2, 0x4E); DPA(c3, 0x4E);
            DPA(c4, 0x4E); DPA(c5, 0x4E); DPA(c6, 0x4E); DPA(c7, 0x4E);
            DPA(c0, 0xB1); DPA(c1, 0xB1); DPA(c2, 0xB1); DPA(c3, 0xB1);
            DPA(c4, 0xB1); DPA(c5, 0xB1); DPA(c6, 0xB1); DPA(c7, 0xB1);
            if (kq == 0) {
                float h0 = fmaxf(c0 + biasr, 0.f), h1 = fmaxf(c1 + biasr, 0.f);
                float h2 = fmaxf(c2 + biasr, 0.f), h3 = fmaxf(c3 + biasr, 0.f);
                float h4 = fmaxf(c4 + biasr, 0.f), h5 = fmaxf(c5 + biasr, 0.f);
                float h6 = fmaxf(c6 + biasr, 0.f), h7 = fmaxf(c7 + biasr, 0.f);
                uint4 pk;
                pk.x = pkrtz(h0, h1); pk.y = pkrtz(h2, h3);
                pk.z = pkrtz(h4, h5); pk.w = pkrtz(h6, h7);
                // coherent publish for the other 15 blocks
                u64* dst8 = (u64*)(hT + (size_t)nxt * HT_HALF
                                   + ((size_t)G * AH + row0 + r) * NB);
                astore(dst8,     ((u64)pk.y << 32) | pk.x);
                astore(dst8 + 1, ((u64)pk.w << 32) | pk.z);
                // self-copy straight into next slab (skip L3 for own rows)
                slab[nxt * COLT + row0 + r] = pk;
                float* hp = hnew + cur * NRW * HNEW_PAD + r * HNEW_PAD;
                hp[0] = h0; hp[1] = h1; hp[2] = h2; hp[3] = h3;
                hp[4] = h4; hp[5] = h5; hp[6] = h6; hp[7] = h7;
            }
            // per-wave publish flag: own astores drained, no barrier, no tid0 wait
            asm volatile("s_waitcnt vmcnt(0)" ::: "memory");
            if (lane == 0)
                __hip_atomic_store(myflag, (uint32_t)(t + 1), __ATOMIC_RELAXED,
                                   __HIP_MEMORY_SCOPE_AGENT);
        } else if (t > 0) {
            // ---- wave 15: out-writes for t-1 (no compute, no flag) ----
            const float* hp = hnew + ((t - 1) & 1) * NRW * HNEW_PAD;
            for (int i = lane; i < NB * NRW; i += 64) {
                int bb = i / NRW, d = i - bb * NRW;
                out[(((size_t)(g * NB + bb)) * NT + (t - 1)) * HH + (size_t)a * AH + row0 + d]
                    = hp[d * HNEW_PAD + bb];
            }
        }
    }
    __syncthreads();
    // ---- epilogue: output for the final step (all threads) ----
    {
        const float* hp = hnew + ((NT - 1) & 1) * NRW * HNEW_PAD;
        for (int i = tid; i < NB * NRW; i += NTHREADS) {
            int bb = i / NRW, d = i - bb * NRW;
            out[(((size_t)(g * NB + bb)) * NT + (NT - 1)) * HH + (size_t)a * AH + row0 + d]
                = hp[d * HNEW_PAD + bb];
        }
    }
}

extern "C" void kernel_launch(void* const* d_in, const int* in_sizes, int n_in,
                              void* d_out, int out_size, void* d_ws, size_t ws_size,
                              hipStream_t stream)
{
    const float* x    = (const float*)d_in[0];
    const float* Wih  = (const float*)d_in[1];
    const float* bih  = (const float*)d_in[2];
    const float* Whh  = (const float*)d_in[3];
    const float* bhh  = (const float*)d_in[4];
    const float* mask = (const float*)d_in[5];
    float* out = (float*)d_out;

    char* ws = (char*)d_ws;
    uint32_t* ent = (uint32_t*)(ws);
    uint32_t* cnt = (uint32_t*)(ws + ENT_BYTES);
    uint16_t* xT2 = (uint16_t*)(ws + ENT_BYTES + CNT_BYTES);
    uint16_t* hT  = (uint16_t*)(ws + ENT_BYTES + CNT_BYTES + XT2_BYTES);
    uint32_t* flg = (uint32_t*)(ws + ENT_BYTES + CNT_BYTES + XT2_BYTES + HT_BYTES);

    init_ws_kernel<<<512, 256, 0, stream>>>(flg, (uint32_t*)hT);
    build_ell_kernel<<<(HH * 64 + 255) / 256, 256, 0, stream>>>(Whh, mask, Wih, ent, cnt);
    xt_kernel<<<(NT * NI * NBATCH + 255) / 256, 256, 0, stream>>>(x, xT2);

    hipFuncSetAttribute((const void*)rnn_kernel,
                        hipFuncAttributeMaxDynamicSharedMemorySize, SMEM_ALLOC);

    void* args[] = {(void*)&ent, (void*)&cnt, (void*)&xT2, (void*)&hT, (void*)&flg,
                    (void*)&bih, (void*)&bhh, (void*)&out};
    hipLaunchCooperativeKernel((const void*)rnn_kernel, dim3(NBLOCKS), dim3(NTHREADS),
                               args, SMEM_ALLOC, stream);
}

// Round 12
// 1249.983 us; speedup vs baseline: 1.7772x; 1.7772x over previous
//
#include <hip/hip_runtime.h>
#include <stdint.h>
#include <stddef.h>

#define HH 3840
#define AH 1920
#define NI 18
#define NT 256
#define NBATCH 64
#define KMAX 224      // ELL capacity per row, incl. 18 input entries
#define JSLOT 28      // KMAX/8 per-lane entry slots
#define NRW 120       // rows per block
#define NB 8          // batches per group
#define NGROUP 16     // 2 areas * 8 batch-tiles
#define NBLK_G 16     // blocks per group
#define NBLOCKS 256
#define NTHREADS 1024
#define COLS 1920
#define COLT 1938     // 1920 h cols + 18 x cols
#define HNEW_PAD 9

// ---- ws layout (bytes) ----
#define ENT_BYTES ((size_t)HH * KMAX * 4)            // 3,440,640
#define CNT_BYTES ((size_t)HH * 4)                   // 15,360
#define XT2_BYTES ((size_t)NT * NI * NBATCH * 2)     // 589,824 (f16)
#define HT_HALF   ((size_t)NGROUP * AH * NB)         // u16 elems per buffer = 245,760
#define HT_BYTES  (2 * HT_HALF * 2)                  // 983,040 (double buffered)
#define FLAG_ELEMS ((size_t)NGROUP * NBLK_G * 32)    // 8192 (128B-padded slots)
#define PC_ELEMS  16

// ---- LDS (dynamic) ----
#define SLAB_B    (COLT * 16)                // 31,008 per buffer
#define OFF_HNEW  (2 * SLAB_B)               // 62,016
#define HNEW_B    (2 * NRW * HNEW_PAD * 4)   // 8,640 (double buffered)
#define SMEM_USED (OFF_HNEW + HNEW_B)        // 70,656
#define SMEM_ALLOC 83968                     // force 1 block/CU

#define AS1 __attribute__((address_space(1)))
#define AS3 __attribute__((address_space(3)))

typedef unsigned long long u64;

__device__ __forceinline__ float lo16(uint32_t u) {
    union { uint16_t q; _Float16 h; } c; c.q = (uint16_t)u; return (float)c.h;
}
__device__ __forceinline__ uint16_t f2h_bits(float f) {
    union { _Float16 h; uint16_t u; } c; c.h = (_Float16)f; return c.u;
}
__device__ __forceinline__ uint32_t pkrtz(float x, float y) {
    typedef __fp16 h2 __attribute__((ext_vector_type(2)));
    union { h2 h; uint32_t u; } c; c.h = __builtin_amdgcn_cvt_pkrtz(x, y); return c.u;
}
__device__ __forceinline__ void gll16(const void* g, void* l) {
    __builtin_amdgcn_global_load_lds((const AS1 uint32_t*)g, (AS3 uint32_t*)l, 16, 0, 0);
}
__device__ __forceinline__ void astore(u64* p, u64 v) {
    __hip_atomic_store(p, v, __ATOMIC_RELAXED, __HIP_MEMORY_SCOPE_AGENT);
}
__device__ __forceinline__ uint32_t sel8(const uint32_t v[8], int b) {
    uint32_t x = v[0];
    #pragma unroll
    for (int i = 1; i < 8; ++i) x = (b == i) ? v[i] : x;
    return x;
}
__device__ __forceinline__ u64 sel8_64(const u64 v[8], int b) {
    u64 x = v[0];
    #pragma unroll
    for (int i = 1; i < 8; ++i) x = (b == i) ? v[i] : x;
    return x;
}
#define SWZ(v, pat) __uint_as_float(__builtin_amdgcn_ds_swizzle(__float_as_uint(v), pat))
#define DPA(c, ctrl) c += __uint_as_float(__builtin_amdgcn_mov_dpp(__float_as_uint(c), ctrl, 0xF, 0xF, true))
// single-instruction f16(lo/hi of %1) * f32(%2) + f32 acc
#define FMIX_LO(acc, h2, w) asm("v_fma_mix_f32 %0, %1, %2, %0 op_sel:[0,0,0] op_sel_hi:[1,0,0]" : "+v"(acc) : "v"(h2), "v"(w))
#define FMIX_HI(acc, h2, w) asm("v_fma_mix_f32 %0, %1, %2, %0 op_sel:[1,0,0] op_sel_hi:[1,0,0]" : "+v"(acc) : "v"(h2), "v"(w))

__global__ void init_ws_kernel(uint32_t* __restrict__ flg, uint32_t* __restrict__ ht0) {
    size_t i = (size_t)blockIdx.x * blockDim.x + threadIdx.x;
    if (i < FLAG_ELEMS + PC_ELEMS) flg[i] = 0;
    if (i < HT_HALF / 2) ht0[i] = 0;   // zero h buffer 0 (h_{-1} = 0), u32 view
}

// one wave per row. Entries are emitted in BANK-INTERLEAVED order: bucket by
// col&7, rank key = k*8+bucket (k = index within bucket), dense rank ->
// positions [8j,8j+8) hold 8 distinct bank-quads while buckets last, so the
// gather's 8 kq-lanes per row hit 8 distinct LDS bank groups.
__global__ void build_ell_kernel(const float* __restrict__ Whh, const float* __restrict__ mask,
                                 const float* __restrict__ Wih,
                                 uint32_t* __restrict__ ent, uint32_t* __restrict__ cnt) {
    int gw = (int)((blockIdx.x * blockDim.x + threadIdx.x) >> 6);
    int lane = threadIdx.x & 63;
    if (gw >= HH) return;
    const int d = gw;
    const int area = (d >= AH) ? 1 : 0;
    const float* mrow = mask + (size_t)d * HH + (size_t)area * AH;
    const float* wrow = Whh + (size_t)d * HH + (size_t)area * AH;
    uint32_t* erow = ent + (size_t)d * KMAX;
    const u64 below = ((u64)1 << lane) - 1;

    uint32_t sz[8] = {0, 0, 0, 0, 0, 0, 0, 0};
    // pass 0: bucket sizes
    for (int c0 = 0; c0 <= AH; c0 += 64) {
        bool isx = (c0 == AH);
        bool pred;
        if (isx) pred = (lane < NI);
        else     pred = (mrow[c0 + lane] != 0.0f);
        int b = lane & 7;                      // (c0+lane)&7 == lane&7 (c0%64==0); x cols 1920+lane too
        #pragma unroll
        for (int bb = 0; bb < 8; ++bb)
            sz[bb] += (uint32_t)__popcll(__ballot(pred && (b == bb)));
    }
    // pass 1: ranked emit
    uint32_t run[8] = {0, 0, 0, 0, 0, 0, 0, 0};
    for (int c0 = 0; c0 <= AH; c0 += 64) {
        bool isx = (c0 == AH);
        int col; bool pred; float wval;
        if (isx) {
            col = COLS + lane; pred = (lane < NI);
            wval = pred ? Wih[(size_t)d * NI + lane] : 0.0f;
        } else {
            col = c0 + lane;
            float m = mrow[col];
            pred = (m != 0.0f);
            wval = pred ? wrow[col] * m : 0.0f;
        }
        int b = lane & 7;
        u64 bal[8];
        #pragma unroll
        for (int bb = 0; bb < 8; ++bb) bal[bb] = __ballot(pred && (b == bb));
        if (pred) {
            uint32_t k = sel8(run, b) + (uint32_t)__popcll(sel8_64(bal, b) & below);
            uint32_t rank = k;
            #pragma unroll
            for (int bb = 0; bb < 8; ++bb) {
                uint32_t cap = (bb < b) ? (k + 1) : k;
                uint32_t add = (sz[bb] < cap) ? sz[bb] : cap;
                rank += (bb == b) ? 0u : add;
            }
            if (rank < KMAX) erow[rank] = ((uint32_t)col << 16) | (uint32_t)f2h_bits(wval);
        }
        #pragma unroll
        for (int bb = 0; bb < 8; ++bb) run[bb] += (uint32_t)__popcll(bal[bb]);
    }
    uint32_t tot = sz[0] + sz[1] + sz[2] + sz[3] + sz[4] + sz[5] + sz[6] + sz[7];
    if (lane == 0) cnt[d] = (tot < KMAX) ? tot : KMAX;
}

__global__ void xt_kernel(const float* __restrict__ x, uint16_t* __restrict__ xT2) {
    int i = blockIdx.x * blockDim.x + threadIdx.x;  // [t][i][b]
    if (i >= NT * NI * NBATCH) return;
    int b = i % NBATCH;
    int rest = i / NBATCH;
    int ii = rest % NI;
    int t = rest / NI;
    xT2[i] = f2h_bits(x[((size_t)b * NT + t) * NI + ii]);
}

__global__ __launch_bounds__(NTHREADS, 4) void rnn_kernel(
    const uint32_t* __restrict__ ent, const uint32_t* __restrict__ cnt,
    const uint16_t* __restrict__ xT2, uint16_t* __restrict__ hT,
    uint32_t* __restrict__ flg,
    const float* __restrict__ bih, const float* __restrict__ bhh,
    float* __restrict__ out)
{
    extern __shared__ char smem[];
    uint4* slab = (uint4*)smem;                  // [2][COLT] f16x8
    float* hnew = (float*)(smem + OFF_HNEW);     // [2][NRW][9]

    const int tid = threadIdx.x;
    const int G = blockIdx.x & 15, role = blockIdx.x >> 4;   // placement-independent
    const int a = G >> 3, g = G & 7;
    const int row0 = role * NRW;                 // area-local
    const size_t mySlot = ((size_t)G * NBLK_G + role) * 32;

    const int wv = tid >> 6, lane = tid & 63;
    const int ro = lane >> 3;          // 0..7 row within wave
    const int kq = lane & 7;           // 0..7 k-stripe
    const int r  = wv * 8 + ro;        // block-local row (valid for wv < 15)

    // ---- hoist step-invariant entries into VGPRs ----
    float wj[JSLOT];
    int   aj[JSLOT];
    float biasr = 0.f;
    int wm = 0;
    if (wv < 15) {
        const int gRow = a * AH + row0 + r;
        const int n = (int)cnt[gRow];
        biasr = bih[gRow] + bhh[gRow];
        int jmax = (n > kq) ? ((n - kq + 7) >> 3) : 0;
        const uint32_t* ep = ent + (size_t)gRow * KMAX;
        #pragma unroll
        for (int j = 0; j < JSLOT; ++j) {
            uint32_t e = (j < jmax) ? ep[kq + 8 * j] : 0u;
            aj[j] = (int)((e >> 16) * 16);           // byte offset within one slab buffer
            wj[j] = (j < jmax) ? lo16(e) : 0.0f;
        }
        wm = jmax;
        #pragma unroll
        for (int s = 1; s < 64; s <<= 1) {
            int ov = __shfl_xor(wm, s, 64);
            wm = (ov > wm) ? ov : wm;                // wave-uniform trip count
        }
    }

    for (int t = 0; t < NT; ++t) {
        const int cur = t & 1, nxt = cur ^ 1;
        // ---- x tail for this step (const data, DMA into current slab) ----
        if (wv == 0 && lane < NI)
            gll16(xT2 + ((size_t)t * NI + lane) * NBATCH + g * NB,
                  &slab[cur * COLT + COLS + lane]);
        // ---- per-wave poll + stage: wave w owns producer (role+w)&15 ----
        if (wv > 0 || t == 0) {
            const int p = (role + wv) & 15;
            if (t > 0) {
                const uint32_t* sl = flg + ((size_t)G * NBLK_G + p) * 32;
                int guard = 0;
                while (__hip_atomic_load(sl, __ATOMIC_RELAXED, __HIP_MEMORY_SCOPE_AGENT)
                       < (uint32_t)t && ++guard < (1 << 15))
                    __builtin_amdgcn_s_sleep(1);
            }
            const uint4* sp = (const uint4*)(hT + (size_t)cur * HT_HALF
                                             + ((size_t)G * AH + p * NRW) * NB);
            const int l2 = (lane < 56) ? (64 + lane) : lane;
            uint4 v0, v1;
            asm volatile("global_load_dwordx4 %0, %2, off sc0 sc1\n\t"
                         "global_load_dwordx4 %1, %3, off sc0 sc1\n\t"
                         "s_waitcnt vmcnt(0)"
                         : "=&v"(v0), "=&v"(v1)
                         : "v"(sp + lane), "v"(sp + l2)
                         : "memory");
            uint4* dst = slab + cur * COLT + p * NRW;
            dst[lane] = v0;
            dst[l2] = v1;
        }
        __syncthreads();   // slab[cur] complete (also drains x-tail DMA)

        // ---- out-writes for t-1 on wave 15 (idle during compute) ----
        if (wv == 15 && t > 0) {
            const float* hp = hnew + ((t - 1) & 1) * NRW * HNEW_PAD;
            for (int i = lane; i < NB * NRW; i += 64) {
                int bb = i / NRW, d = i - bb * NRW;
                out[(((size_t)(g * NB + bb)) * NT + (t - 1)) * HH + (size_t)a * AH + row0 + d]
                    = hp[d * HNEW_PAD + bb];
            }
        }

        // ---- compute ----
        if (wv < 15) {
            const char* sb = (const char*)(slab + cur * COLT);
            float c0 = 0.f, c1 = 0.f, c2 = 0.f, c3 = 0.f, c4 = 0.f, c5 = 0.f, c6 = 0.f, c7 = 0.f;
            #pragma unroll
            for (int j = 0; j < JSLOT; ++j) {
                if (j >= wm) break;
                const uint4 hv = *(const uint4*)(sb + aj[j]);
                const float wf = wj[j];
                FMIX_LO(c0, hv.x, wf); FMIX_HI(c1, hv.x, wf);
                FMIX_LO(c2, hv.y, wf); FMIX_HI(c3, hv.y, wf);
                FMIX_LO(c4, hv.z, wf); FMIX_HI(c5, hv.z, wf);
                FMIX_LO(c6, hv.w, wf); FMIX_HI(c7, hv.w, wf);
            }
            // reduce across kq: xor4 via ds_swizzle, xor2/xor1 via DPP quad_perm
            c0 += SWZ(c0, 0x101F); c1 += SWZ(c1, 0x101F); c2 += SWZ(c2, 0x101F); c3 += SWZ(c3, 0x101F);
            c4 += SWZ(c4, 0x101F); c5 += SWZ(c5, 0x101F); c6 += SWZ(c6, 0x101F); c7 += SWZ(c7, 0x101F);
            DPA(c0, 0x4E); DPA(c1, 0x4E); DPA(c2, 0x4E); DPA(c3, 0x4E);
            DPA(c4, 0x4E); DPA(c5, 0x4E); DPA(c6, 0x4E); DPA(c7, 0x4E);
            DPA(c0, 0xB1); DPA(c1, 0xB1); DPA(c2, 0xB1); DPA(c3, 0xB1);
            DPA(c4, 0xB1); DPA(c5, 0xB1); DPA(c6, 0xB1); DPA(c7, 0xB1);
            if (kq == 0) {
                float h0 = fmaxf(c0 + biasr, 0.f), h1 = fmaxf(c1 + biasr, 0.f);
                float h2 = fmaxf(c2 + biasr, 0.f), h3 = fmaxf(c3 + biasr, 0.f);
                float h4 = fmaxf(c4 + biasr, 0.f), h5 = fmaxf(c5 + biasr, 0.f);
                float h6 = fmaxf(c6 + biasr, 0.f), h7 = fmaxf(c7 + biasr, 0.f);
                uint4 pk;
                pk.x = pkrtz(h0, h1); pk.y = pkrtz(h2, h3);
                pk.z = pkrtz(h4, h5); pk.w = pkrtz(h6, h7);
                // coherent publish for the other 15 blocks
                u64* dst8 = (u64*)(hT + (size_t)nxt * HT_HALF
                                   + ((size_t)G * AH + row0 + r) * NB);
                astore(dst8,     ((u64)pk.y << 32) | pk.x);
                astore(dst8 + 1, ((u64)pk.w << 32) | pk.z);
                // self-copy straight into next slab (skip L3 for own rows)
                slab[nxt * COLT + row0 + r] = pk;
                float* hp = hnew + cur * NRW * HNEW_PAD + r * HNEW_PAD;
                hp[0] = h0; hp[1] = h1; hp[2] = h2; hp[3] = h3;
                hp[4] = h4; hp[5] = h5; hp[6] = h6; hp[7] = h7;
            }
        }
        __syncthreads();   // drains all astores (compiler vmcnt) + hnew complete

        if (tid == 0)
            __hip_atomic_store(flg + mySlot, (uint32_t)(t + 1), __ATOMIC_RELAXED,
                               __HIP_MEMORY_SCOPE_AGENT);
    }
    // ---- epilogue: output for the final step ----
    {
        const float* hp = hnew + ((NT - 1) & 1) * NRW * HNEW_PAD;
        for (int i = tid; i < NB * NRW; i += NTHREADS) {
            int bb = i / NRW, d = i - bb * NRW;
            out[(((size_t)(g * NB + bb)) * NT + (NT - 1)) * HH + (size_t)a * AH + row0 + d]
                = hp[d * HNEW_PAD + bb];
        }
    }
}

extern "C" void kernel_launch(void* const* d_in, const int* in_sizes, int n_in,
                              void* d_out, int out_size, void* d_ws, size_t ws_size,
                              hipStream_t stream)
{
    const float* x    = (const float*)d_in[0];
    const float* Wih  = (const float*)d_in[1];
    const float* bih  = (const float*)d_in[2];
    const float* Whh  = (const float*)d_in[3];
    const float* bhh  = (const float*)d_in[4];
    const float* mask = (const float*)d_in[5];
    float* out = (float*)d_out;

    char* ws = (char*)d_ws;
    uint32_t* ent = (uint32_t*)(ws);
    uint32_t* cnt = (uint32_t*)(ws + ENT_BYTES);
    uint16_t* xT2 = (uint16_t*)(ws + ENT_BYTES + CNT_BYTES);
    uint16_t* hT  = (uint16_t*)(ws + ENT_BYTES + CNT_BYTES + XT2_BYTES);
    uint32_t* flg = (uint32_t*)(ws + ENT_BYTES + CNT_BYTES + XT2_BYTES + HT_BYTES);

    init_ws_kernel<<<512, 256, 0, stream>>>(flg, (uint32_t*)hT);
    build_ell_kernel<<<(HH * 64 + 255) / 256, 256, 0, stream>>>(Whh, mask, Wih, ent, cnt);
    xt_kernel<<<(NT * NI * NBATCH + 255) / 256, 256, 0, stream>>>(x, xT2);

    hipFuncSetAttribute((const void*)rnn_kernel,
                        hipFuncAttributeMaxDynamicSharedMemorySize, SMEM_ALLOC);

    void* args[] = {(void*)&ent, (void*)&cnt, (void*)&xT2, (void*)&hT, (void*)&flg,
                    (void*)&bih, (void*)&bhh, (void*)&out};
    hipLaunchCooperativeKernel((const void*)rnn_kernel, dim3(NBLOCKS), dim3(NTHREADS),
                               args, SMEM_ALLOC, stream);
}

// Round 14
// 1135.798 us; speedup vs baseline: 1.9559x; 1.1005x over previous
//
#include <hip/hip_runtime.h>
#include <stdint.h>
#include <stddef.h>

#define HH 3840
#define AH 1920
#define NI 18
#define NT 256
#define NBATCH 64
#define KMAX 224      // ELL capacity per row, incl. 18 input entries
#define JSLOT 28      // KMAX/8 per-lane entry slots
#define NRW 120       // rows per block
#define NB 8          // batches per group
#define NGROUP 16     // 2 areas * 8 batch-tiles
#define NBLK_G 16     // blocks per group
#define NBLOCKS 256
#define NTHREADS 1024
#define COLS 1920
#define COLT 1938     // 1920 h cols + 18 x cols
#define HNEW_PAD 9

// ---- ws layout (bytes) ----
#define ENT_BYTES ((size_t)HH * KMAX * 4)            // 3,440,640
#define CNT_BYTES ((size_t)HH * 4)                   // 15,360
#define XT2_BYTES ((size_t)NT * NI * NBATCH * 2)     // 589,824 (f16)
#define HT_HALF   ((size_t)NGROUP * AH * NB)         // u16 elems per buffer = 245,760
#define HT_BYTES  (2 * HT_HALF * 2)                  // 983,040 (double buffered)
#define FLAG_ELEMS ((size_t)NGROUP * NBLK_G * 32)    // 8192 (128B-padded slots)
#define PC_ELEMS  16
#define PERM_BYTES ((size_t)HH * 4)                  // 15,360 each (pos/inv/deg)

// ---- LDS (dynamic) ----
#define SLAB_B    (COLT * 16)                // 31,008 per buffer
#define OFF_HNEW  (2 * SLAB_B)               // 62,016
#define HNEW_B    (2 * NRW * HNEW_PAD * 4)   // 8,640 (double buffered)
#define OFF_IPERM (OFF_HNEW + HNEW_B)        // 70,656
#define SMEM_USED (OFF_IPERM + NRW * 4)      // 71,136
#define SMEM_ALLOC 83968                     // force 1 block/CU

#define AS1 __attribute__((address_space(1)))
#define AS3 __attribute__((address_space(3)))

typedef unsigned long long u64;

__device__ __forceinline__ float lo16(uint32_t u) {
    union { uint16_t q; _Float16 h; } c; c.q = (uint16_t)u; return (float)c.h;
}
__device__ __forceinline__ uint16_t f2h_bits(float f) {
    union { _Float16 h; uint16_t u; } c; c.h = (_Float16)f; return c.u;
}
__device__ __forceinline__ uint32_t pkrtz(float x, float y) {
    typedef __fp16 h2 __attribute__((ext_vector_type(2)));
    union { h2 h; uint32_t u; } c; c.h = __builtin_amdgcn_cvt_pkrtz(x, y); return c.u;
}
__device__ __forceinline__ void gll16(const void* g, void* l) {
    __builtin_amdgcn_global_load_lds((const AS1 uint32_t*)g, (AS3 uint32_t*)l, 16, 0, 0);
}
__device__ __forceinline__ void astore(u64* p, u64 v) {
    __hip_atomic_store(p, v, __ATOMIC_RELAXED, __HIP_MEMORY_SCOPE_AGENT);
}
__device__ __forceinline__ uint32_t sel8(const uint32_t v[8], int b) {
    uint32_t x = v[0];
    #pragma unroll
    for (int i = 1; i < 8; ++i) x = (b == i) ? v[i] : x;
    return x;
}
__device__ __forceinline__ u64 sel8_64(const u64 v[8], int b) {
    u64 x = v[0];
    #pragma unroll
    for (int i = 1; i < 8; ++i) x = (b == i) ? v[i] : x;
    return x;
}
#define SWZ(v, pat) __uint_as_float(__builtin_amdgcn_ds_swizzle(__float_as_uint(v), pat))
#define DPA(c, ctrl) c += __uint_as_float(__builtin_amdgcn_mov_dpp(__float_as_uint(c), ctrl, 0xF, 0xF, true))
// single-instruction f16(lo/hi of %1) * f32(%2) + f32 acc
#define FMIX_LO(acc, h2, w) asm("v_fma_mix_f32 %0, %1, %2, %0 op_sel:[0,0,0] op_sel_hi:[1,0,0]" : "+v"(acc) : "v"(h2), "v"(w))
#define FMIX_HI(acc, h2, w) asm("v_fma_mix_f32 %0, %1, %2, %0 op_sel:[1,0,0] op_sel_hi:[1,0,0]" : "+v"(acc) : "v"(h2), "v"(w))

__global__ void init_ws_kernel(uint32_t* __restrict__ flg, uint32_t* __restrict__ ht0) {
    size_t i = (size_t)blockIdx.x * blockDim.x + threadIdx.x;
    if (i < FLAG_ELEMS + PC_ELEMS) flg[i] = 0;
    if (i < HT_HALF / 2) ht0[i] = 0;   // zero h buffer 0 (h_{-1} = 0), u32 view
}

// one wave per orig row: degree = nnz(mask row) + NI
__global__ void deg_kernel(const float* __restrict__ mask, uint32_t* __restrict__ deg) {
    int gw = (int)((blockIdx.x * blockDim.x + threadIdx.x) >> 6);
    int lane = threadIdx.x & 63;
    if (gw >= HH) return;
    int area = (gw >= AH) ? 1 : 0;
    const float* mrow = mask + (size_t)gw * HH + (size_t)area * AH;
    uint32_t n = 0;
    for (int c0 = 0; c0 < AH; c0 += 64)
        n += (uint32_t)__popcll(__ballot(mrow[c0 + lane] != 0.0f));
    if (lane == 0) deg[gw] = n + NI;
}

// per orig row: rank by (deg desc, idx asc) within its area; chunk-of-8 dealt
// round-robin over 16 blocks -> position. pos/inv arrays are area-local values.
__global__ void perm_kernel(const uint32_t* __restrict__ deg,
                            uint32_t* __restrict__ posA, uint32_t* __restrict__ invA) {
    int d = blockIdx.x * blockDim.x + threadIdx.x;
    if (d >= HH) return;
    int area = (d >= AH) ? 1 : 0;
    int i = d - area * AH;
    const uint32_t* db = deg + (size_t)area * AH;
    uint32_t di = db[i];
    uint32_t rank = 0;
    for (int j = 0; j < AH; ++j) {
        uint32_t dj = db[j];
        rank += (dj > di || (dj == di && j < i)) ? 1u : 0u;
    }
    uint32_t chunk = rank >> 3, o = rank & 7;
    uint32_t pos = (chunk & 15) * NRW + (chunk >> 4) * 8 + o;
    posA[d] = pos;
    invA[(size_t)area * AH + pos] = (uint32_t)i;
}

// one wave per DEST POSITION; entries reference permuted SOURCE POSITIONS and
// are emitted bank-interleaved (bucket by pos&7, dense rank by k*8+bucket).
__global__ void build_ell_kernel(const float* __restrict__ Whh, const float* __restrict__ mask,
                                 const float* __restrict__ Wih,
                                 const uint32_t* __restrict__ posA, const uint32_t* __restrict__ invA,
                                 uint32_t* __restrict__ ent, uint32_t* __restrict__ cnt) {
    int gw = (int)((blockIdx.x * blockDim.x + threadIdx.x) >> 6);
    int lane = threadIdx.x & 63;
    if (gw >= HH) return;
    const int area = (gw >= AH) ? 1 : 0;
    const int ol = (int)invA[gw];                    // orig local row
    const size_t og = (size_t)area * AH + ol;        // orig global row
    const float* mrow = mask + og * HH + (size_t)area * AH;
    const float* wrow = Whh + og * HH + (size_t)area * AH;
    const uint32_t* pA = posA + (size_t)area * AH;
    uint32_t* erow = ent + (size_t)gw * KMAX;
    const u64 below = ((u64)1 << lane) - 1;

    uint32_t sz[8] = {0, 0, 0, 0, 0, 0, 0, 0};
    for (int c0 = 0; c0 <= AH; c0 += 64) {
        bool isx = (c0 == AH);
        bool pred; int b;
        if (isx) { pred = (lane < NI); b = lane & 7; }
        else     { pred = (mrow[c0 + lane] != 0.0f); b = (int)(pA[c0 + lane] & 7); }
        #pragma unroll
        for (int bb = 0; bb < 8; ++bb)
            sz[bb] += (uint32_t)__popcll(__ballot(pred && (b == bb)));
    }
    uint32_t run[8] = {0, 0, 0, 0, 0, 0, 0, 0};
    for (int c0 = 0; c0 <= AH; c0 += 64) {
        bool isx = (c0 == AH);
        int col; bool pred; float wval; int b;
        if (isx) {
            col = COLS + lane; pred = (lane < NI); b = lane & 7;
            wval = pred ? Wih[og * NI + lane] : 0.0f;
        } else {
            float m = mrow[c0 + lane];
            pred = (m != 0.0f);
            col = (int)pA[c0 + lane];                // permuted source position
            b = col & 7;
            wval = pred ? wrow[c0 + lane] * m : 0.0f;
        }
        u64 bal[8];
        #pragma unroll
        for (int bb = 0; bb < 8; ++bb) bal[bb] = __ballot(pred && (b == bb));
        if (pred) {
            uint32_t k = sel8(run, b) + (uint32_t)__popcll(sel8_64(bal, b) & below);
            uint32_t rank = k;
            #pragma unroll
            for (int bb = 0; bb < 8; ++bb) {
                uint32_t cap = (bb < b) ? (k + 1) : k;
                uint32_t add = (sz[bb] < cap) ? sz[bb] : cap;
                rank += (bb == b) ? 0u : add;
            }
            if (rank < KMAX) erow[rank] = ((uint32_t)col << 16) | (uint32_t)f2h_bits(wval);
        }
        #pragma unroll
        for (int bb = 0; bb < 8; ++bb) run[bb] += (uint32_t)__popcll(bal[bb]);
    }
    uint32_t tot = sz[0] + sz[1] + sz[2] + sz[3] + sz[4] + sz[5] + sz[6] + sz[7];
    if (lane == 0) cnt[gw] = (tot < KMAX) ? tot : KMAX;
}

__global__ void xt_kernel(const float* __restrict__ x, uint16_t* __restrict__ xT2) {
    int i = blockIdx.x * blockDim.x + threadIdx.x;  // [t][i][b]
    if (i >= NT * NI * NBATCH) return;
    int b = i % NBATCH;
    int rest = i / NBATCH;
    int ii = rest % NI;
    int t = rest / NI;
    xT2[i] = f2h_bits(x[((size_t)b * NT + t) * NI + ii]);
}

__global__ __launch_bounds__(NTHREADS, 4) void rnn_kernel(
    const uint32_t* __restrict__ ent, const uint32_t* __restrict__ cnt,
    const uint16_t* __restrict__ xT2, uint16_t* __restrict__ hT,
    uint32_t* __restrict__ flg, const uint32_t* __restrict__ invA,
    const float* __restrict__ bih, const float* __restrict__ bhh,
    float* __restrict__ out)
{
    extern __shared__ char smem[];
    uint4* slab = (uint4*)smem;                    // [2][COLT] f16x8 (permuted rows)
    float* hnew = (float*)(smem + OFF_HNEW);       // [2][NRW][9] (position-indexed)
    uint32_t* iperm = (uint32_t*)(smem + OFF_IPERM);  // [NRW] pos -> orig local row

    const int tid = threadIdx.x;
    const int G = blockIdx.x & 15, role = blockIdx.x >> 4;   // placement-independent
    const int a = G >> 3, g = G & 7;
    const int row0 = role * NRW;                 // area-local POSITION base
    const size_t mySlot = ((size_t)G * NBLK_G + role) * 32;

    const int wv = tid >> 6, lane = tid & 63;
    const int ro = lane >> 3;          // 0..7 row within wave
    const int kq = lane & 7;           // 0..7 k-stripe
    const int r  = wv * 8 + ro;        // block-local position (valid for wv < 15)

    // ---- prologue: iperm + step-invariant entries into VGPRs ----
    for (int i = tid; i < NRW; i += NTHREADS)
        iperm[i] = invA[(size_t)a * AH + row0 + i];

    float wj[JSLOT];
    int   aj[JSLOT];
    float biasr = 0.f;
    int wm = 0;
    if (wv < 15) {
        const int gRow = a * AH + row0 + r;          // position-global
        const int ol = (int)invA[gRow];              // orig local row
        const int n = (int)cnt[gRow];
        biasr = bih[a * AH + ol] + bhh[a * AH + ol];
        int jmax = (n > kq) ? ((n - kq + 7) >> 3) : 0;
        const uint32_t* ep = ent + (size_t)gRow * KMAX;
        #pragma unroll
        for (int j = 0; j < JSLOT; ++j) {
            uint32_t e = (j < jmax) ? ep[kq + 8 * j] : 0u;
            aj[j] = (int)((e >> 16) * 16);           // byte offset within one slab buffer
            wj[j] = (j < jmax) ? lo16(e) : 0.0f;
        }
        wm = jmax;
        #pragma unroll
        for (int s = 1; s < 64; s <<= 1) {
            int ov = __shfl_xor(wm, s, 64);
            wm = (ov > wm) ? ov : wm;                // wave-uniform trip count
        }
    }

    for (int t = 0; t < NT; ++t) {
        const int cur = t & 1, nxt = cur ^ 1;
        // ---- x tail for this step (const data, DMA into current slab) ----
        if (wv == 0 && lane < NI)
            gll16(xT2 + ((size_t)t * NI + lane) * NBATCH + g * NB,
                  &slab[cur * COLT + COLS + lane]);
        // ---- per-wave poll + stage: wave w owns producer (role+w)&15 ----
        if (wv > 0 || t == 0) {
            const int p = (role + wv) & 15;
            if (t > 0) {
                const uint32_t* sl = flg + ((size_t)G * NBLK_G + p) * 32;
                int guard = 0;
                while (__hip_atomic_load(sl, __ATOMIC_RELAXED, __HIP_MEMORY_SCOPE_AGENT)
                       < (uint32_t)t && ++guard < (1 << 15))
                    __builtin_amdgcn_s_sleep(1);
            }
            const uint4* sp = (const uint4*)(hT + (size_t)cur * HT_HALF
                                             + ((size_t)G * AH + p * NRW) * NB);
            const int l2 = (lane < 56) ? (64 + lane) : lane;
            uint4 v0, v1;
            asm volatile("global_load_dwordx4 %0, %2, off sc0 sc1\n\t"
                         "global_load_dwordx4 %1, %3, off sc0 sc1\n\t"
                         "s_waitcnt vmcnt(0)"
                         : "=&v"(v0), "=&v"(v1)
                         : "v"(sp + lane), "v"(sp + l2)
                         : "memory");
            uint4* dst = slab + cur * COLT + p * NRW;
            dst[lane] = v0;
            dst[l2] = v1;
        }
        __syncthreads();   // slab[cur] complete (also drains x-tail DMA; iperm ready)

        // ---- out-writes for t-1 on wave 15 (idle during compute) ----
        if (wv == 15 && t > 0) {
            const float* hp = hnew + ((t - 1) & 1) * NRW * HNEW_PAD;
            for (int i = lane; i < NB * NRW; i += 64) {
                int bb = i / NRW, d = i - bb * NRW;
                out[(((size_t)(g * NB + bb)) * NT + (t - 1)) * HH + (size_t)a * AH + iperm[d]]
                    = hp[d * HNEW_PAD + bb];
            }
        }

        // ---- compute ----
        if (wv < 15) {
            const char* sb = (const char*)(slab + cur * COLT);
            float c0 = 0.f, c1 = 0.f, c2 = 0.f, c3 = 0.f, c4 = 0.f, c5 = 0.f, c6 = 0.f, c7 = 0.f;
            #pragma unroll
            for (int j = 0; j < JSLOT; ++j) {
                if (j >= wm) break;
                const uint4 hv = *(const uint4*)(sb + aj[j]);
                const float wf = wj[j];
                FMIX_LO(c0, hv.x, wf); FMIX_HI(c1, hv.x, wf);
                FMIX_LO(c2, hv.y, wf); FMIX_HI(c3, hv.y, wf);
                FMIX_LO(c4, hv.z, wf); FMIX_HI(c5, hv.z, wf);
                FMIX_LO(c6, hv.w, wf); FMIX_HI(c7, hv.w, wf);
            }
            c0 += SWZ(c0, 0x101F); c1 += SWZ(c1, 0x101F); c2 += SWZ(c2, 0x101F); c3 += SWZ(c3, 0x101F);
            c4 += SWZ(c4, 0x101F); c5 += SWZ(c5, 0x101F); c6 += SWZ(c6, 0x101F); c7 += SWZ(c7, 0x101F);
            DPA(c0, 0x4E); DPA(c1, 0x4E); DPA(c2, 0x4E); DPA(c3, 0x4E);
            DPA(c4, 0x4E); DPA(c5, 0x4E); DPA(c6, 0x4E); DPA(c7, 0x4E);
            DPA(c0, 0xB1); DPA(c1, 0xB1); DPA(c2, 0xB1); DPA(c3, 0xB1);
            DPA(c4, 0xB1); DPA(c5, 0xB1); DPA(c6, 0xB1); DPA(c7, 0xB1);
            if (kq == 0) {
                float h0 = fmaxf(c0 + biasr, 0.f), h1 = fmaxf(c1 + biasr, 0.f);
                float h2 = fmaxf(c2 + biasr, 0.f), h3 = fmaxf(c3 + biasr, 0.f);
                float h4 = fmaxf(c4 + biasr, 0.f), h5 = fmaxf(c5 + biasr, 0.f);
                float h6 = fmaxf(c6 + biasr, 0.f), h7 = fmaxf(c7 + biasr, 0.f);
                uint4 pk;
                pk.x = pkrtz(h0, h1); pk.y = pkrtz(h2, h3);
                pk.z = pkrtz(h4, h5); pk.w = pkrtz(h6, h7);
                // coherent publish for the other 15 blocks (position-contiguous)
                u64* dst8 = (u64*)(hT + (size_t)nxt * HT_HALF
                                   + ((size_t)G * AH + row0 + r) * NB);
                astore(dst8,     ((u64)pk.y << 32) | pk.x);
                astore(dst8 + 1, ((u64)pk.w << 32) | pk.z);
                // self-copy straight into next slab (skip L3 for own rows)
                slab[nxt * COLT + row0 + r] = pk;
                float* hp = hnew + cur * NRW * HNEW_PAD + r * HNEW_PAD;
                hp[0] = h0; hp[1] = h1; hp[2] = h2; hp[3] = h3;
                hp[4] = h4; hp[5] = h5; hp[6] = h6; hp[7] = h7;
            }
        }
        __syncthreads();   // drains all astores (compiler vmcnt) + hnew complete

        if (tid == 0)
            __hip_atomic_store(flg + mySlot, (uint32_t)(t + 1), __ATOMIC_RELAXED,
                               __HIP_MEMORY_SCOPE_AGENT);
    }
    // ---- epilogue: output for the final step ----
    {
        const float* hp = hnew + ((NT - 1) & 1) * NRW * HNEW_PAD;
        for (int i = tid; i < NB * NRW; i += NTHREADS) {
            int bb = i / NRW, d = i - bb * NRW;
            out[(((size_t)(g * NB + bb)) * NT + (NT - 1)) * HH + (size_t)a * AH + iperm[d]]
                = hp[d * HNEW_PAD + bb];
        }
    }
}

extern "C" void kernel_launch(void* const* d_in, const int* in_sizes, int n_in,
                              void* d_out, int out_size, void* d_ws, size_t ws_size,
                              hipStream_t stream)
{
    const float* x    = (const float*)d_in[0];
    const float* Wih  = (const float*)d_in[1];
    const float* bih  = (const float*)d_in[2];
    const float* Whh  = (const float*)d_in[3];
    const float* bhh  = (const float*)d_in[4];
    const float* mask = (const float*)d_in[5];
    float* out = (float*)d_out;

    char* ws = (char*)d_ws;
    uint32_t* ent = (uint32_t*)(ws);
    uint32_t* cnt = (uint32_t*)(ws + ENT_BYTES);
    uint16_t* xT2 = (uint16_t*)(ws + ENT_BYTES + CNT_BYTES);
    uint16_t* hT  = (uint16_t*)(ws + ENT_BYTES + CNT_BYTES + XT2_BYTES);
    uint32_t* flg = (uint32_t*)(ws + ENT_BYTES + CNT_BYTES + XT2_BYTES + HT_BYTES);
    char* ptail   = ws + ENT_BYTES + CNT_BYTES + XT2_BYTES + HT_BYTES
                    + (FLAG_ELEMS + PC_ELEMS) * 4;
    uint32_t* posA = (uint32_t*)(ptail);
    uint32_t* invA = (uint32_t*)(ptail + PERM_BYTES);
    uint32_t* degA = (uint32_t*)(ptail + 2 * PERM_BYTES);

    init_ws_kernel<<<512, 256, 0, stream>>>(flg, (uint32_t*)hT);
    deg_kernel<<<(HH * 64 + 255) / 256, 256, 0, stream>>>(mask, degA);
    perm_kernel<<<(HH + 255) / 256, 256, 0, stream>>>(degA, posA, invA);
    build_ell_kernel<<<(HH * 64 + 255) / 256, 256, 0, stream>>>(Whh, mask, Wih, posA, invA, ent, cnt);
    xt_kernel<<<(NT * NI * NBATCH + 255) / 256, 256, 0, stream>>>(x, xT2);

    hipFuncSetAttribute((const void*)rnn_kernel,
                        hipFuncAttributeMaxDynamicSharedMemorySize, SMEM_ALLOC);

    void* args[] = {(void*)&ent, (void*)&cnt, (void*)&xT2, (void*)&hT, (void*)&flg,
                    (void*)&invA, (void*)&bih, (void*)&bhh, (void*)&out};
    hipLaunchCooperativeKernel((const void*)rnn_kernel, dim3(NBLOCKS), dim3(NTHREADS),
                               args, SMEM_ALLOC, stream);
}